// Round 4
// baseline (456.687 us; speedup 1.0000x reference)
//
#include <hip/hip_runtime.h>
#include <hip/hip_bf16.h>

// Problem constants: B=8,N=64,T=128,E=128,H=8,R=4,DH=16
constexpr int cE  = 128;
constexpr int cR  = 4;
constexpr int cNT = 65536;   // B*N*T tokens

typedef short s8v  __attribute__((ext_vector_type(8)));   // 8 bf16 MFMA frag
typedef unsigned short u8v __attribute__((ext_vector_type(8)));
typedef float f4v  __attribute__((ext_vector_type(4)));   // MFMA accumulator

static __device__ __forceinline__ unsigned short f2bf(float x) {
    union { float f; unsigned int u; } v; v.f = x;
    unsigned int r = v.u + 0x7fffu + ((v.u >> 16) & 1u);  // RNE
    return (unsigned short)(r >> 16);
}
static __device__ __forceinline__ float bf2f(unsigned short u) {
    union { unsigned int u; float f; } v; v.u = ((unsigned int)u) << 16;
    return v.f;
}

// ---------------------------------------------------------------------------
// Prolog (merged weights+biases):
//   blocks 0..447:  wqkv[w][f][g] = sum_e in_w[w*E+f][e]*W_{q,k,v}[e][g] (w0*0.25)
//                   meff[e1][r*E+e] = sum_f fc_w[e1][r*E+f]*out_w[f][e]
//   blocks 448..449: effective biases
// ---------------------------------------------------------------------------
__global__ __launch_bounds__(256) void k_prep(
    const float* __restrict__ Wq, const float* __restrict__ Wk, const float* __restrict__ Wv,
    const float* __restrict__ in_w, const float* __restrict__ out_w, const float* __restrict__ fc_w,
    const float* __restrict__ bq, const float* __restrict__ bk, const float* __restrict__ bv,
    const float* __restrict__ in_b, const float* __restrict__ out_b, const float* __restrict__ fc_b,
    unsigned short* __restrict__ wqkv, unsigned short* __restrict__ meff,
    float* __restrict__ bqkv, float* __restrict__ beff)
{
    int bid = blockIdx.x;
    if (bid < 448) {
        int idx = bid * 256 + threadIdx.x;
        if (idx < 3 * cE * cE) {
            int w   = idx >> 14;
            int rem = idx & (cE * cE - 1);
            int f = rem >> 7, g = rem & 127;
            const float* Wsel = (w == 0) ? Wq : ((w == 1) ? Wk : Wv);
            const float* iw = in_w + (size_t)(w * cE + f) * cE;
            float s = 0.f;
            #pragma unroll 4
            for (int e = 0; e < cE; ++e) s += iw[e] * Wsel[e * cE + g];
            if (w == 0) s *= 0.25f;        // 1/sqrt(DH) folded into q-path
            wqkv[idx] = f2bf(s);
        } else {
            int i2 = idx - 3 * cE * cE;    // < 65536
            int e1 = i2 >> 9;
            int c  = i2 & 511;             // r*128+e
            const float* fw = fc_w + (size_t)e1 * 512 + (c >> 7) * cE;
            int ee = c & 127;
            float s = 0.f;
            #pragma unroll 4
            for (int f = 0; f < cE; ++f) s += fw[f] * out_w[f * cE + ee];
            meff[(size_t)e1 * 512 + c] = f2bf(s);
        }
    } else {
        int idx = (bid - 448) * 256 + threadIdx.x;   // 0..511
        if (idx < 384) {
            int w = idx >> 7, f = idx & 127;
            const float* bsel = (w == 0) ? bq : ((w == 1) ? bk : bv);
            const float* iw = in_w + (size_t)(w * cE + f) * cE;
            float s = 0.f;
            for (int e = 0; e < cE; ++e) s += iw[e] * bsel[e];
            s += in_b[w * cE + f];
            if (w == 0) s *= 0.25f;
            bqkv[idx] = s;
        } else {
            int f = idx - 384;
            float s = 0.f;
            for (int c = 0; c < 512; ++c) s += fc_w[(size_t)f * 512 + c] * out_b[c & 127];
            beff[f] = s + fc_b[f];
        }
    }
}

// ---------------------------------------------------------------------------
// Main fused kernel. grid 2048 x 256 thr; 32 tokens/block, 4 chunks of 8.
// LDS 35.5 KB -> 4 blocks/CU (vs r3: 53 KB + grid 512 -> 2 blocks/CU, occ 22%).
// uAO unions the staging tile (sA, live: stage->QKV) with the attention
// output tile (sO, live: attn->final GEMM) — disjoint live ranges per chunk.
// ---------------------------------------------------------------------------
#define TOKB   32    // tokens per block  (cNT/2048)
#define TOKC   8     // tokens per chunk
#define PITCH  136   // bf16 elems; row stride 272B: 16B-aligned, 4-bank rotation
#define OPITCH 520   // bf16 elems; row stride 1040B: 16B-aligned, 4-bank rotation

__global__ __launch_bounds__(256, 4) void k_main(
    const float* __restrict__ node, const float* __restrict__ sub,
    const unsigned short* __restrict__ wqkv,   // [3][128][128] bf16 (B^T layout)
    const unsigned short* __restrict__ meff,   // [128][512]    bf16 (B^T layout)
    const float* __restrict__ bqkv,            // [3*128]
    const float* __restrict__ beff,            // [128]
    float* __restrict__ out)                   // [NT][128]
{
    // sA view: 32 rows x PITCH (4352 hw, 8704 B); sO view: 8 rows x OPITCH (4160 hw)
    __shared__ unsigned short uAO[32 * PITCH];             // 8704 B
    __shared__ unsigned short sQKV[3][cR * TOKC][PITCH];   // 26112 B
    __shared__ float sBias[3 * cE];                        // 1536 B -> total 36352 B

    const int tid  = threadIdx.x;
    const int lane = tid & 63;
    const int wv   = tid >> 6;      // wave 0..3
    const int l15  = lane & 15;
    const int lq   = lane >> 4;     // quad 0..3
    const int ct0  = wv * 2;        // each wave owns 2 of 8 col-tiles

    // 384 entries, 256 threads -> grid-stride (r2 bug fix retained)
    for (int i = tid; i < 3 * cE; i += 256) sBias[i] = bqkv[i];

    const int tokBlock = blockIdx.x * TOKB;

    for (int chunk = 0; chunk < TOKB / TOKC; ++chunk) {
        const int tokBase = tokBlock + chunk * TOKC;
        __syncthreads();  // prev chunk's sO/sQKV readers done; publishes sBias (chunk 0)

        // ---- stage combined -> sA view of uAO (bf16), vectorized
        {   // node: 8 tok x 128 e = 256 float4, 1 per thread -> packed b64 write
            int tok = tid >> 5;
            int e4  = (tid & 31) * 4;
            float4 v = *(const float4*)(node + (size_t)(tokBase + tok) * cE + e4);
            ushort4 w4;
            w4.x = f2bf(v.x); w4.y = f2bf(v.y); w4.z = f2bf(v.z); w4.w = f2bf(v.w);
            *(ushort4*)&uAO[(tok * cR) * PITCH + e4] = w4;
        }
        #pragma unroll
        for (int it = 0; it < 3; ++it) {   // sub: 768 float4, 3 per thread
            int i4  = tid + it * 256;      // 0..767
            int tok = i4 / 96;             // 96 float4 per token (384 floats)
            int p0  = (i4 - tok * 96) * 4;
            float4 v = *(const float4*)(sub + (size_t)(tokBase + tok) * 384 + p0);
            float vv[4] = {v.x, v.y, v.z, v.w};
            #pragma unroll
            for (int c = 0; c < 4; ++c) {
                int p = p0 + c;
                int e = p / 3, j = p - e * 3;     // sub layout [tok][e][j]
                uAO[(tok * cR + 1 + j) * PITCH + e] = f2bf(vv[c]);
            }
        }
        __syncthreads();

        // ---- QKV GEMM: [32 rows x 128] = sA[32x128] @ Weff^T, per weight
        for (int w = 0; w < 3; ++w) {
            const unsigned short* wbase = wqkv + (size_t)w * cE * cE;
            f4v acc[2][2];
            #pragma unroll
            for (int a = 0; a < 2; ++a)
                #pragma unroll
                for (int b = 0; b < 2; ++b) acc[a][b] = (f4v){0.f, 0.f, 0.f, 0.f};
            #pragma unroll
            for (int kc = 0; kc < 4; ++kc) {
                int koff = kc * 32 + lq * 8;
                s8v a0 = *(const s8v*)&uAO[(0 * 16 + l15) * PITCH + koff];
                s8v a1 = *(const s8v*)&uAO[(1 * 16 + l15) * PITCH + koff];
                #pragma unroll
                for (int c = 0; c < 2; ++c) {
                    int f = (ct0 + c) * 16 + l15;
                    s8v b = *(const s8v*)(wbase + (size_t)f * cE + koff);
                    acc[0][c] = __builtin_amdgcn_mfma_f32_16x16x32_bf16(a0, b, acc[0][c], 0, 0, 0);
                    acc[1][c] = __builtin_amdgcn_mfma_f32_16x16x32_bf16(a1, b, acc[1][c], 0, 0, 0);
                }
            }
            // C layout: col = lane&15, row = quad*4 + reg  [m89-verified]
            #pragma unroll
            for (int rt = 0; rt < 2; ++rt)
                #pragma unroll
                for (int c = 0; c < 2; ++c) {
                    int f = (ct0 + c) * 16 + l15;
                    float bias = sBias[w * cE + f];
                    #pragma unroll
                    for (int i = 0; i < 4; ++i) {
                        int row = rt * 16 + lq * 4 + i;
                        sQKV[w][row][f] = f2bf(acc[rt][c][i] + bias);
                    }
                }
        }
        __syncthreads();   // sQKV ready; sA view of uAO now dead

        // ---- attention: 256 thr = 8 tok x 8 heads x 4 q-rows, fp32 softmax
        {
            int tok = tid >> 5;
            int h   = (tid >> 2) & 7;
            int r   = tid & 3;
            const unsigned short* qp = &sQKV[0][tok * cR + r][h * 16];
            u8v q0 = *(const u8v*)qp, q1 = *(const u8v*)(qp + 8);
            float q[16];
            #pragma unroll
            for (int d = 0; d < 8; ++d) { q[d] = bf2f(q0[d]); q[8 + d] = bf2f(q1[d]); }
            float sc[4];
            #pragma unroll
            for (int s = 0; s < 4; ++s) {
                const unsigned short* kp = &sQKV[1][tok * cR + s][h * 16];
                u8v k0 = *(const u8v*)kp, k1 = *(const u8v*)(kp + 8);
                float t = 0.f;
                #pragma unroll
                for (int d = 0; d < 8; ++d) t += q[d] * bf2f(k0[d]) + q[8 + d] * bf2f(k1[d]);
                sc[s] = t;
            }
            float m = fmaxf(fmaxf(sc[0], sc[1]), fmaxf(sc[2], sc[3]));
            float p[4], l = 0.f;
            #pragma unroll
            for (int s = 0; s < 4; ++s) { p[s] = __expf(sc[s] - m); l += p[s]; }
            float inv = 1.f / l;
            float o[16];
            #pragma unroll
            for (int d = 0; d < 16; ++d) o[d] = 0.f;
            #pragma unroll
            for (int s = 0; s < 4; ++s) {
                float w = p[s] * inv;
                const unsigned short* vp = &sQKV[2][tok * cR + s][h * 16];
                u8v v0 = *(const u8v*)vp, v1 = *(const u8v*)(vp + 8);
                #pragma unroll
                for (int d = 0; d < 8; ++d) { o[d] += w * bf2f(v0[d]); o[8 + d] += w * bf2f(v1[d]); }
            }
            // write o -> sO view of uAO (sA dead since last barrier)
            unsigned int pk[8];
            #pragma unroll
            for (int d2 = 0; d2 < 8; ++d2)
                pk[d2] = (unsigned int)f2bf(o[2 * d2]) | ((unsigned int)f2bf(o[2 * d2 + 1]) << 16);
            uint4* op = (uint4*)&uAO[tok * OPITCH + r * cE + h * 16];
            op[0] = make_uint4(pk[0], pk[1], pk[2], pk[3]);
            op[1] = make_uint4(pk[4], pk[5], pk[6], pk[7]);
        }
        __syncthreads();   // sO ready

        // ---- final GEMM: [8 tok x 128] = sO[8x512] @ Meff^T  (M=8 on 16-row tiles)
        {
            f4v acc[2];
            acc[0] = (f4v){0.f, 0.f, 0.f, 0.f};
            acc[1] = (f4v){0.f, 0.f, 0.f, 0.f};
            int arow = l15 & 7;            // rows 8..15 duplicate 0..7; discarded at store
            #pragma unroll 4
            for (int kc = 0; kc < 16; ++kc) {
                int koff = kc * 32 + lq * 8;
                s8v a = *(const s8v*)&uAO[arow * OPITCH + koff];
                #pragma unroll
                for (int c = 0; c < 2; ++c) {
                    int e1 = (ct0 + c) * 16 + l15;
                    s8v b = *(const s8v*)(meff + (size_t)e1 * 512 + koff);
                    acc[c] = __builtin_amdgcn_mfma_f32_16x16x32_bf16(a, b, acc[c], 0, 0, 0);
                }
            }
            if (lq < 2) {                  // valid C rows 0..7 (= tokens)
                #pragma unroll
                for (int c = 0; c < 2; ++c) {
                    int e1 = (ct0 + c) * 16 + l15;
                    float bb = beff[e1];
                    #pragma unroll
                    for (int i = 0; i < 4; ++i) {
                        int tok = lq * 4 + i;
                        out[(size_t)(tokBase + tok) * cE + e1] = acc[c][i] + bb;
                    }
                }
            }
        }
    }
}

// ---------------------------------------------------------------------------
extern "C" void kernel_launch(void* const* d_in, const int* in_sizes, int n_in,
                              void* d_out, int out_size, void* d_ws, size_t ws_size,
                              hipStream_t stream) {
    const float* node  = (const float*)d_in[0];
    const float* sub   = (const float*)d_in[1];
    const float* Wq    = (const float*)d_in[2];
    const float* bq    = (const float*)d_in[3];
    const float* Wk    = (const float*)d_in[4];
    const float* bk    = (const float*)d_in[5];
    const float* Wv    = (const float*)d_in[6];
    const float* bv    = (const float*)d_in[7];
    const float* in_w  = (const float*)d_in[8];
    const float* in_b  = (const float*)d_in[9];
    const float* out_w = (const float*)d_in[10];
    const float* out_b = (const float*)d_in[11];
    const float* fc_w  = (const float*)d_in[12];
    const float* fc_b  = (const float*)d_in[13];

    unsigned short* ws_wqkv = (unsigned short*)d_ws;                 // 3*128*128 bf16
    unsigned short* ws_meff = ws_wqkv + 3 * cE * cE;                 // 128*512  bf16
    float* ws_bqkv = (float*)((char*)d_ws + (size_t)(3 * cE * cE + cE * cR * cE) * 2);
    float* ws_beff = ws_bqkv + 3 * cE;

    k_prep<<<dim3(450), dim3(256), 0, stream>>>(Wq, Wk, Wv, in_w, out_w, fc_w,
                                                bq, bk, bv, in_b, out_b, fc_b,
                                                ws_wqkv, ws_meff, ws_bqkv, ws_beff);
    k_main<<<dim3(cNT / TOKB), dim3(256), 0, stream>>>(node, sub, ws_wqkv, ws_meff,
                                                       ws_bqkv, ws_beff, (float*)d_out);
}

// Round 5
// 345.278 us; speedup vs baseline: 1.3227x; 1.3227x over previous
//
#include <hip/hip_runtime.h>
#include <hip/hip_bf16.h>

// Problem constants: B=8,N=64,T=128,E=128,H=8,R=4,DH=16
constexpr int cE  = 128;
constexpr int cR  = 4;
constexpr int cNT = 65536;   // B*N*T tokens

typedef short s8v  __attribute__((ext_vector_type(8)));   // 8 bf16 MFMA frag
typedef unsigned short u8v __attribute__((ext_vector_type(8)));
typedef float f4v  __attribute__((ext_vector_type(4)));   // MFMA accumulator

static __device__ __forceinline__ unsigned short f2bf(float x) {
    union { float f; unsigned int u; } v; v.f = x;
    unsigned int r = v.u + 0x7fffu + ((v.u >> 16) & 1u);  // RNE
    return (unsigned short)(r >> 16);
}
static __device__ __forceinline__ float bf2f(unsigned short u) {
    union { unsigned int u; float f; } v; v.u = ((unsigned int)u) << 16;
    return v.f;
}

// ---------------------------------------------------------------------------
// Prolog (merged weights+biases):
//   blocks 0..447:  wqkv[w][f][g] = sum_e in_w[w*E+f][e]*W_{q,k,v}[e][g] (w0*0.25)
//                   meff[e1][r*E+e] = sum_f fc_w[e1][r*E+f]*out_w[f][e]
//   blocks 448..449: effective biases
// ---------------------------------------------------------------------------
__global__ __launch_bounds__(256) void k_prep(
    const float* __restrict__ Wq, const float* __restrict__ Wk, const float* __restrict__ Wv,
    const float* __restrict__ in_w, const float* __restrict__ out_w, const float* __restrict__ fc_w,
    const float* __restrict__ bq, const float* __restrict__ bk, const float* __restrict__ bv,
    const float* __restrict__ in_b, const float* __restrict__ out_b, const float* __restrict__ fc_b,
    unsigned short* __restrict__ wqkv, unsigned short* __restrict__ meff,
    float* __restrict__ bqkv, float* __restrict__ beff)
{
    int bid = blockIdx.x;
    if (bid < 448) {
        int idx = bid * 256 + threadIdx.x;
        if (idx < 3 * cE * cE) {
            int w   = idx >> 14;
            int rem = idx & (cE * cE - 1);
            int f = rem >> 7, g = rem & 127;
            const float* Wsel = (w == 0) ? Wq : ((w == 1) ? Wk : Wv);
            const float* iw = in_w + (size_t)(w * cE + f) * cE;
            float s = 0.f;
            #pragma unroll 4
            for (int e = 0; e < cE; ++e) s += iw[e] * Wsel[e * cE + g];
            if (w == 0) s *= 0.25f;        // 1/sqrt(DH) folded into q-path
            wqkv[idx] = f2bf(s);
        } else {
            int i2 = idx - 3 * cE * cE;    // < 65536
            int e1 = i2 >> 9;
            int c  = i2 & 511;             // r*128+e
            const float* fw = fc_w + (size_t)e1 * 512 + (c >> 7) * cE;
            int ee = c & 127;
            float s = 0.f;
            #pragma unroll 4
            for (int f = 0; f < cE; ++f) s += fw[f] * out_w[f * cE + ee];
            meff[(size_t)e1 * 512 + c] = f2bf(s);
        }
    } else {
        int idx = (bid - 448) * 256 + threadIdx.x;   // 0..511
        if (idx < 384) {
            int w = idx >> 7, f = idx & 127;
            const float* bsel = (w == 0) ? bq : ((w == 1) ? bk : bv);
            const float* iw = in_w + (size_t)(w * cE + f) * cE;
            float s = 0.f;
            for (int e = 0; e < cE; ++e) s += iw[e] * bsel[e];
            s += in_b[w * cE + f];
            if (w == 0) s *= 0.25f;
            bqkv[idx] = s;
        } else {
            int f = idx - 384;
            float s = 0.f;
            for (int c = 0; c < 512; ++c) s += fc_w[(size_t)f * 512 + c] * out_b[c & 127];
            beff[f] = s + fc_b[f];
        }
    }
}

// ---------------------------------------------------------------------------
// Main fused kernel. grid 2048 x 256 thr; 32 tokens/block, 4 chunks of 8.
// LDS 35.5 KB -> 4 blocks/CU by LDS; VGPR must stay <=128 for 4 waves/EU.
// r4 post-mortem: __launch_bounds__(256,4) clamped VGPR to 64 -> scratch
// spills (+440 MB HBM traffic, dur 232->306). NO min-waves arg: r3's body
// compiled to 104 VGPR naturally, which sustains 4 blocks/CU.
// uAO unions the staging tile (sA, live: stage->QKV) with the attention
// output tile (sO, live: attn->final GEMM) — disjoint live ranges per chunk.
// ---------------------------------------------------------------------------
#define TOKB   32    // tokens per block  (cNT/2048)
#define TOKC   8     // tokens per chunk
#define PITCH  136   // bf16 elems; row stride 272B: 16B-aligned, 4-bank rotation
#define OPITCH 520   // bf16 elems; row stride 1040B: 16B-aligned, 4-bank rotation

__global__ __launch_bounds__(256) void k_main(
    const float* __restrict__ node, const float* __restrict__ sub,
    const unsigned short* __restrict__ wqkv,   // [3][128][128] bf16 (B^T layout)
    const unsigned short* __restrict__ meff,   // [128][512]    bf16 (B^T layout)
    const float* __restrict__ bqkv,            // [3*128]
    const float* __restrict__ beff,            // [128]
    float* __restrict__ out)                   // [NT][128]
{
    // sA view: 32 rows x PITCH (8704 B); sO view: 8 rows x OPITCH (8320 B)
    __shared__ unsigned short uAO[32 * PITCH];             // 8704 B
    __shared__ unsigned short sQKV[3][cR * TOKC][PITCH];   // 26112 B
    __shared__ float sBias[3 * cE];                        // 1536 B -> total 36352 B

    const int tid  = threadIdx.x;
    const int lane = tid & 63;
    const int wv   = tid >> 6;      // wave 0..3
    const int l15  = lane & 15;
    const int lq   = lane >> 4;     // quad 0..3
    const int ct0  = wv * 2;        // each wave owns 2 of 8 col-tiles

    // 384 entries, 256 threads -> grid-stride (r2 bug fix retained)
    for (int i = tid; i < 3 * cE; i += 256) sBias[i] = bqkv[i];

    const int tokBlock = blockIdx.x * TOKB;

    for (int chunk = 0; chunk < TOKB / TOKC; ++chunk) {
        const int tokBase = tokBlock + chunk * TOKC;
        __syncthreads();  // prev chunk's sO/sQKV readers done; publishes sBias (chunk 0)

        // ---- stage combined -> sA view of uAO (bf16), vectorized
        {   // node: 8 tok x 128 e = 256 float4, 1 per thread -> packed b64 write
            int tok = tid >> 5;
            int e4  = (tid & 31) * 4;
            float4 v = *(const float4*)(node + (size_t)(tokBase + tok) * cE + e4);
            ushort4 w4;
            w4.x = f2bf(v.x); w4.y = f2bf(v.y); w4.z = f2bf(v.z); w4.w = f2bf(v.w);
            *(ushort4*)&uAO[(tok * cR) * PITCH + e4] = w4;
        }
        #pragma unroll
        for (int it = 0; it < 3; ++it) {   // sub: 768 float4, 3 per thread
            int i4  = tid + it * 256;      // 0..767
            int tok = i4 / 96;             // 96 float4 per token (384 floats)
            int p0  = (i4 - tok * 96) * 4;
            float4 v = *(const float4*)(sub + (size_t)(tokBase + tok) * 384 + p0);
            float vv[4] = {v.x, v.y, v.z, v.w};
            #pragma unroll
            for (int c = 0; c < 4; ++c) {
                int p = p0 + c;
                int e = p / 3, j = p - e * 3;     // sub layout [tok][e][j]
                uAO[(tok * cR + 1 + j) * PITCH + e] = f2bf(vv[c]);
            }
        }
        __syncthreads();

        // ---- QKV GEMM: [32 rows x 128] = sA[32x128] @ Weff^T, per weight
        for (int w = 0; w < 3; ++w) {
            const unsigned short* wbase = wqkv + (size_t)w * cE * cE;
            f4v acc[2][2];
            #pragma unroll
            for (int a = 0; a < 2; ++a)
                #pragma unroll
                for (int b = 0; b < 2; ++b) acc[a][b] = (f4v){0.f, 0.f, 0.f, 0.f};
            #pragma unroll
            for (int kc = 0; kc < 4; ++kc) {
                int koff = kc * 32 + lq * 8;
                s8v a0 = *(const s8v*)&uAO[(0 * 16 + l15) * PITCH + koff];
                s8v a1 = *(const s8v*)&uAO[(1 * 16 + l15) * PITCH + koff];
                #pragma unroll
                for (int c = 0; c < 2; ++c) {
                    int f = (ct0 + c) * 16 + l15;
                    s8v b = *(const s8v*)(wbase + (size_t)f * cE + koff);
                    acc[0][c] = __builtin_amdgcn_mfma_f32_16x16x32_bf16(a0, b, acc[0][c], 0, 0, 0);
                    acc[1][c] = __builtin_amdgcn_mfma_f32_16x16x32_bf16(a1, b, acc[1][c], 0, 0, 0);
                }
            }
            // C layout: col = lane&15, row = quad*4 + reg  [m89-verified]
            #pragma unroll
            for (int rt = 0; rt < 2; ++rt)
                #pragma unroll
                for (int c = 0; c < 2; ++c) {
                    int f = (ct0 + c) * 16 + l15;
                    float bias = sBias[w * cE + f];
                    #pragma unroll
                    for (int i = 0; i < 4; ++i) {
                        int row = rt * 16 + lq * 4 + i;
                        sQKV[w][row][f] = f2bf(acc[rt][c][i] + bias);
                    }
                }
        }
        __syncthreads();   // sQKV ready; sA view of uAO now dead

        // ---- attention: 256 thr = 8 tok x 8 heads x 4 q-rows, fp32 softmax
        {
            int tok = tid >> 5;
            int h   = (tid >> 2) & 7;
            int r   = tid & 3;
            const unsigned short* qp = &sQKV[0][tok * cR + r][h * 16];
            u8v q0 = *(const u8v*)qp, q1 = *(const u8v*)(qp + 8);
            float q[16];
            #pragma unroll
            for (int d = 0; d < 8; ++d) { q[d] = bf2f(q0[d]); q[8 + d] = bf2f(q1[d]); }
            float sc[4];
            #pragma unroll
            for (int s = 0; s < 4; ++s) {
                const unsigned short* kp = &sQKV[1][tok * cR + s][h * 16];
                u8v k0 = *(const u8v*)kp, k1 = *(const u8v*)(kp + 8);
                float t = 0.f;
                #pragma unroll
                for (int d = 0; d < 8; ++d) t += q[d] * bf2f(k0[d]) + q[8 + d] * bf2f(k1[d]);
                sc[s] = t;
            }
            float m = fmaxf(fmaxf(sc[0], sc[1]), fmaxf(sc[2], sc[3]));
            float p[4], l = 0.f;
            #pragma unroll
            for (int s = 0; s < 4; ++s) { p[s] = __expf(sc[s] - m); l += p[s]; }
            float inv = 1.f / l;
            float o[16];
            #pragma unroll
            for (int d = 0; d < 16; ++d) o[d] = 0.f;
            #pragma unroll
            for (int s = 0; s < 4; ++s) {
                float w = p[s] * inv;
                const unsigned short* vp = &sQKV[2][tok * cR + s][h * 16];
                u8v v0 = *(const u8v*)vp, v1 = *(const u8v*)(vp + 8);
                #pragma unroll
                for (int d = 0; d < 8; ++d) { o[d] += w * bf2f(v0[d]); o[8 + d] += w * bf2f(v1[d]); }
            }
            // write o -> sO view of uAO (sA dead since last barrier)
            unsigned int pk[8];
            #pragma unroll
            for (int d2 = 0; d2 < 8; ++d2)
                pk[d2] = (unsigned int)f2bf(o[2 * d2]) | ((unsigned int)f2bf(o[2 * d2 + 1]) << 16);
            uint4* op = (uint4*)&uAO[tok * OPITCH + r * cE + h * 16];
            op[0] = make_uint4(pk[0], pk[1], pk[2], pk[3]);
            op[1] = make_uint4(pk[4], pk[5], pk[6], pk[7]);
        }
        __syncthreads();   // sO ready

        // ---- final GEMM: [8 tok x 128] = sO[8x512] @ Meff^T  (M=8 on 16-row tiles)
        {
            f4v acc[2];
            acc[0] = (f4v){0.f, 0.f, 0.f, 0.f};
            acc[1] = (f4v){0.f, 0.f, 0.f, 0.f};
            int arow = l15 & 7;            // rows 8..15 duplicate 0..7; discarded at store
            #pragma unroll 4
            for (int kc = 0; kc < 16; ++kc) {
                int koff = kc * 32 + lq * 8;
                s8v a = *(const s8v*)&uAO[arow * OPITCH + koff];
                #pragma unroll
                for (int c = 0; c < 2; ++c) {
                    int e1 = (ct0 + c) * 16 + l15;
                    s8v b = *(const s8v*)(meff + (size_t)e1 * 512 + koff);
                    acc[c] = __builtin_amdgcn_mfma_f32_16x16x32_bf16(a, b, acc[c], 0, 0, 0);
                }
            }
            if (lq < 2) {                  // valid C rows 0..7 (= tokens)
                #pragma unroll
                for (int c = 0; c < 2; ++c) {
                    int e1 = (ct0 + c) * 16 + l15;
                    float bb = beff[e1];
                    #pragma unroll
                    for (int i = 0; i < 4; ++i) {
                        int tok = lq * 4 + i;
                        out[(size_t)(tokBase + tok) * cE + e1] = acc[c][i] + bb;
                    }
                }
            }
        }
    }
}

// ---------------------------------------------------------------------------
extern "C" void kernel_launch(void* const* d_in, const int* in_sizes, int n_in,
                              void* d_out, int out_size, void* d_ws, size_t ws_size,
                              hipStream_t stream) {
    const float* node  = (const float*)d_in[0];
    const float* sub   = (const float*)d_in[1];
    const float* Wq    = (const float*)d_in[2];
    const float* bq    = (const float*)d_in[3];
    const float* Wk    = (const float*)d_in[4];
    const float* bk    = (const float*)d_in[5];
    const float* Wv    = (const float*)d_in[6];
    const float* bv    = (const float*)d_in[7];
    const float* in_w  = (const float*)d_in[8];
    const float* in_b  = (const float*)d_in[9];
    const float* out_w = (const float*)d_in[10];
    const float* out_b = (const float*)d_in[11];
    const float* fc_w  = (const float*)d_in[12];
    const float* fc_b  = (const float*)d_in[13];

    unsigned short* ws_wqkv = (unsigned short*)d_ws;                 // 3*128*128 bf16
    unsigned short* ws_meff = ws_wqkv + 3 * cE * cE;                 // 128*512  bf16
    float* ws_bqkv = (float*)((char*)d_ws + (size_t)(3 * cE * cE + cE * cR * cE) * 2);
    float* ws_beff = ws_bqkv + 3 * cE;

    k_prep<<<dim3(450), dim3(256), 0, stream>>>(Wq, Wk, Wv, in_w, out_w, fc_w,
                                                bq, bk, bv, in_b, out_b, fc_b,
                                                ws_wqkv, ws_meff, ws_bqkv, ws_beff);
    k_main<<<dim3(cNT / TOKB), dim3(256), 0, stream>>>(node, sub, ws_wqkv, ws_meff,
                                                       ws_bqkv, ws_beff, (float*)d_out);
}